// Round 4
// baseline (5877.659 us; speedup 1.0000x reference)
//
#include <hip/hip_runtime.h>

#define BB 16
#define KD 1024
#define DD 768
#define SS 384
#define HH 192
#define NBLK 64

// ---------- split x into e_i / d_i ----------
__global__ void k_prep(const float* __restrict__ x, float* __restrict__ di, float* __restrict__ ei) {
    int idx = blockIdx.x * 256 + threadIdx.x;       // over BB*KD*SS
    int s = idx % SS;
    long bk = idx / SS;
    const float* xr = x + bk * DD;
    ei[idx] = xr[s < HH ? s : s + HH];
    di[idx] = xr[s < HH ? s + HH : s + 2 * HH];
}

// ---------- generic fp32 NN GEMM: C[M,N] = act(A[M,Kd] @ B[Kd,N] + bias) ----------
template<bool BIAS, bool TANH>
__global__ void k_gemm_nn(const float* __restrict__ A, const float* __restrict__ Bw,
                          const float* __restrict__ bias, float* __restrict__ C,
                          int M, int N, int Kd) {
    __shared__ float As[8][132];
    __shared__ float Bs[8][132];
    int m0 = blockIdx.x * 128, n0 = blockIdx.y * 128;
    int t = threadIdx.x;
    int ty = t / 16, tx = t % 16;
    int arow = t / 2, acol = (t % 2) * 4;
    int brow = t / 32, bcol = (t % 32) * 4;
    float acc[8][8] = {};
    for (int k0 = 0; k0 < Kd; k0 += 8) {
        float4 av = *(const float4*)&A[(long)(m0 + arow) * Kd + k0 + acol];
        float4 bv = *(const float4*)&Bw[(long)(k0 + brow) * N + n0 + bcol];
        __syncthreads();
        As[acol + 0][arow] = av.x; As[acol + 1][arow] = av.y;
        As[acol + 2][arow] = av.z; As[acol + 3][arow] = av.w;
        *(float4*)&Bs[brow][bcol] = bv;
        __syncthreads();
#pragma unroll
        for (int kk = 0; kk < 8; kk++) {
            float a[8], b[8];
            *(float4*)&a[0] = *(const float4*)&As[kk][ty * 8];
            *(float4*)&a[4] = *(const float4*)&As[kk][ty * 8 + 4];
            *(float4*)&b[0] = *(const float4*)&Bs[kk][tx * 8];
            *(float4*)&b[4] = *(const float4*)&Bs[kk][tx * 8 + 4];
#pragma unroll
            for (int i = 0; i < 8; i++)
#pragma unroll
                for (int j = 0; j < 8; j++)
                    acc[i][j] += a[i] * b[j];
        }
    }
#pragma unroll
    for (int i = 0; i < 8; i++) {
        int row = m0 + ty * 8 + i;
#pragma unroll
        for (int j = 0; j < 8; j++) {
            int col = n0 + tx * 8 + j;
            float v = acc[i][j];
            if (BIAS) v += bias[col];
            if (TANH) v = tanhf(v);
            C[(long)row * N + col] = v;
        }
    }
}

// ---------- batched NT GEMM: S[b,j,k] = sum_s T[b,j,s]*Uk[b,k,s]  (raw scores) ----------
__global__ void k_fjk(const float* __restrict__ T, const float* __restrict__ Uk,
                      float* __restrict__ Sout) {
    __shared__ float As[8][132];
    __shared__ float Bs[8][132];
    int b = blockIdx.z;
    const float* Ab = T + (long)b * KD * SS;
    const float* Bb = Uk + (long)b * KD * SS;
    int m0 = blockIdx.x * 128, n0 = blockIdx.y * 128;
    int t = threadIdx.x;
    int ty = t / 16, tx = t % 16;
    int arow = t / 2, acol = (t % 2) * 4;
    float acc[8][8] = {};
    for (int k0 = 0; k0 < SS; k0 += 8) {
        float4 av = *(const float4*)&Ab[(long)(m0 + arow) * SS + k0 + acol];
        float4 bv = *(const float4*)&Bb[(long)(n0 + arow) * SS + k0 + acol];
        __syncthreads();
        As[acol + 0][arow] = av.x; As[acol + 1][arow] = av.y;
        As[acol + 2][arow] = av.z; As[acol + 3][arow] = av.w;
        Bs[acol + 0][arow] = bv.x; Bs[acol + 1][arow] = bv.y;
        Bs[acol + 2][arow] = bv.z; Bs[acol + 3][arow] = bv.w;
        __syncthreads();
#pragma unroll
        for (int kk = 0; kk < 8; kk++) {
            float a[8], b2[8];
            *(float4*)&a[0] = *(const float4*)&As[kk][ty * 8];
            *(float4*)&a[4] = *(const float4*)&As[kk][ty * 8 + 4];
            *(float4*)&b2[0] = *(const float4*)&Bs[kk][tx * 8];
            *(float4*)&b2[4] = *(const float4*)&Bs[kk][tx * 8 + 4];
#pragma unroll
            for (int i = 0; i < 8; i++)
#pragma unroll
                for (int j = 0; j < 8; j++)
                    acc[i][j] += a[i] * b2[j];
        }
    }
#pragma unroll
    for (int i = 0; i < 8; i++) {
        int row = m0 + ty * 8 + i;
#pragma unroll
        for (int j = 0; j < 8; j++) {
            int col = n0 + tx * 8 + j;
            Sout[((long)b * KD + row) * KD + col] = acc[i][j];
        }
    }
}

// ---------- raw root logit g = d_i . fi_w ----------
__global__ void k_firaw(const float* __restrict__ di, const float* __restrict__ fiw, float* __restrict__ g) {
    int w = (blockIdx.x * 256 + threadIdx.x) / 64;
    int lane = threadIdx.x % 64;
    if (w >= BB * KD) return;
    const float* dr = di + (long)w * SS;
    float s = 0.f;
    for (int i = lane; i < SS; i += 64) s += dr[i] * fiw[i];
    for (int off = 32; off; off >>= 1) s += __shfl_down(s, off);
    if (lane == 0) g[w] = s;
}

// ---------- per-column max m[b,k] = max(g[b,k], max_{j!=k} S[b,j,k]) ----------
__global__ void k_colmax(const float* __restrict__ S, const float* __restrict__ g, float* __restrict__ mcol) {
    int idx = blockIdx.x * 256 + threadIdx.x;   // BB*KD
    int b = idx >> 10, k = idx & (KD - 1);
    const float* Sb = S + (long)b * KD * KD;
    float m = g[idx];
    for (int j = 0; j < KD; j++) {
        float v = Sb[(long)j * KD + k];
        m = fmaxf(m, (j == k) ? -3.4e38f : v);
    }
    mcol[idx] = m;
}

// ---------- A = exp(S - m_col), diag zeroed (in place) ----------
__global__ void k_expA(float* __restrict__ S, const float* __restrict__ mcol) {
    int idx = blockIdx.x * 256 + threadIdx.x;   // BB*KD*KD
    int k = idx & (KD - 1);
    int j = (idx >> 10) & (KD - 1);
    int b = idx >> 20;
    S[idx] = (j == k) ? 0.f : expf(S[idx] - mcol[(b << 10) + k]);
}

// ---------- fi = exp(g - m_col) ----------
__global__ void k_fi2(const float* __restrict__ g, const float* __restrict__ mcol, float* __restrict__ fi) {
    int idx = blockIdx.x * 256 + threadIdx.x;   // BB*KD
    fi[idx] = expf(g[idx] - mcol[idx]);
}

// ---------- column sums (fp64) ----------
__global__ void k_colsum_d(const float* __restrict__ A, double* __restrict__ csd) {
    int idx = blockIdx.x * 256 + threadIdx.x;   // BB*KD
    int b = idx >> 10, k = idx & (KD - 1);
    const float* Ab = A + (long)b * KD * KD;
    double s = 0.0;
    for (int j = 0; j < KD; j++) s += (double)Ab[(long)j * KD + k];
    csd[idx] = s;
}

// ---------- build padded T~ (fp64): T[i][j] = L[1+i][1+j] for i,j<1023; identity pad at 1023 ----------
__global__ void k_buildT(const float* __restrict__ A, const double* __restrict__ csd, double* __restrict__ Td) {
    long idx = (long)blockIdx.x * 256 + threadIdx.x;  // BB*KD*KD
    int j = idx & (KD - 1);
    int i = (int)(idx >> 10) & (KD - 1);
    int b = (int)(idx >> 20);
    double v;
    if (i == KD - 1 || j == KD - 1) v = (i == j) ? 1.0 : 0.0;
    else if (i == j) v = csd[(b << 10) + j + 1];
    else v = -(double)A[((long)b << 20) + ((long)(i + 1) << 10) + (j + 1)];
    Td[idx] = v;
}

// ---------- GJ step (fp64): invert diagonal 64x64 block in LDS ----------
__global__ void k_diag_d(double* __restrict__ M, int kb) {
    __shared__ double P[NBLK][NBLK + 1];
    __shared__ double rowbuf[NBLK];
    int b = blockIdx.x;
    double* Mb = M + (long)b * KD * KD;
    int t = threadIdx.x;
    for (int i = t; i < NBLK * NBLK; i += 256)
        P[i / NBLK][i % NBLK] = Mb[(long)(kb + i / NBLK) * KD + kb + i % NBLK];
    __syncthreads();
    int mi = t & 63;
    int c0 = (t >> 6) * 16;
    for (int kk = 0; kk < NBLK; kk++) {
        double p = 1.0 / P[kk][kk];
        double F = P[mi][kk];
        if (t < 64) rowbuf[t] = P[kk][t] * p;
        __syncthreads();
        if (mi == kk) {
            for (int c = c0; c < c0 + 16; c++)
                P[mi][c] = (c == kk) ? p : rowbuf[c];
        } else {
            for (int c = c0; c < c0 + 16; c++)
                P[mi][c] = (c == kk) ? (-F * p) : (P[mi][c] - F * rowbuf[c]);
        }
        __syncthreads();
    }
    for (int i = t; i < NBLK * NBLK; i += 256)
        Mb[(long)(kb + i / NBLK) * KD + kb + i % NBLK] = P[i / NBLK][i % NBLK];
}

// ---------- GJ step (fp64): save old pivot-column block ----------
__global__ void k_savecol_d(const double* __restrict__ M, double* __restrict__ Ft, int kb) {
    int idx = blockIdx.x * 256 + threadIdx.x;     // BB*KD*NBLK
    int c = idx % NBLK;
    int rk = idx / NBLK;
    int r = rk % KD, b = rk / KD;
    Ft[idx] = M[((long)b * KD + r) * KD + kb + c];
}

// ---------- GJ step (fp64): pivot block-row update  M[k,j] = Dinv @ M[k,j], j != ktile ----------
__global__ void k_rowcol_d(double* __restrict__ M, int kb) {
    __shared__ double Ps[NBLK][NBLK + 1];   // Ps[col][row] = Dinv[row][col]
    __shared__ double Ts[16][NBLK + 2];
    int b = blockIdx.y;
    int jt = blockIdx.x;
    int kt = kb / NBLK;
    if (jt >= kt) jt++;                    // grid.x = 15, skip diagonal tile
    int j0 = jt * NBLK;
    double* Mb = M + (long)b * KD * KD;
    int t = threadIdx.x;
    for (int i = t; i < NBLK * NBLK; i += 256) {
        int r = i / NBLK, c = i % NBLK;
        Ps[c][r] = Mb[(long)(kb + r) * KD + kb + c];
    }
    int ty = t >> 4, tx = t & 15;
    double acc[4][4] = {};
    for (int kc = 0; kc < NBLK; kc += 16) {
        __syncthreads();
        for (int i = t; i < 16 * NBLK; i += 256) {
            int r = i / NBLK, c = i % NBLK;
            Ts[r][c] = Mb[(long)(kb + kc + r) * KD + j0 + c];
        }
        __syncthreads();
#pragma unroll
        for (int kk = 0; kk < 16; kk++) {
            double a[4], bv[4];
#pragma unroll
            for (int i = 0; i < 4; i++) a[i] = Ps[kc + kk][ty * 4 + i];
#pragma unroll
            for (int j = 0; j < 4; j++) bv[j] = Ts[kk][tx * 4 + j];
#pragma unroll
            for (int i = 0; i < 4; i++)
#pragma unroll
                for (int j = 0; j < 4; j++)
                    acc[i][j] += a[i] * bv[j];
        }
    }
#pragma unroll
    for (int i = 0; i < 4; i++)
#pragma unroll
        for (int j = 0; j < 4; j++)
            Mb[(long)(kb + ty * 4 + i) * KD + j0 + tx * 4 + j] = acc[i][j];
}

// ---------- GJ step (fp64): trailing elimination + pivot-column update ----------
__global__ void k_elim_d(double* __restrict__ M, const double* __restrict__ Ft, int kb) {
    __shared__ double Fs[16][NBLK + 2];    // Fs[kcol][row]
    __shared__ double Rs[16][132];         // Rs[krow][col]
    int b = blockIdx.z;
    int it = blockIdx.y;
    int kt = kb / NBLK;
    if (it == kt) return;
    int i0 = it * NBLK;
    int j0 = blockIdx.x * 128;
    double* Mb = M + (long)b * KD * KD;
    const double* Fb = Ft + ((long)b * KD + i0) * NBLK;
    const double* Rrow = Mb + (long)kb * KD;
    int t = threadIdx.x, ty = t >> 4, tx = t & 15;
    double acc[4][8] = {};
    for (int kc = 0; kc < NBLK; kc += 16) {
        __syncthreads();
        for (int i = t; i < 16 * NBLK; i += 256) {   // 1024 elems, 4 per thread
            int r = i >> 4, c = i & 15;
            Fs[c][r] = Fb[(long)r * NBLK + kc + c];
        }
        for (int i = t; i < 16 * 128; i += 256) {
            int r = i >> 7, c = i & 127;
            Rs[r][c] = Rrow[(long)(kc + r) * KD + j0 + c];
        }
        __syncthreads();
#pragma unroll
        for (int kk = 0; kk < 16; kk++) {
            double a[4], bv[8];
#pragma unroll
            for (int i = 0; i < 4; i++) a[i] = Fs[kk][ty * 4 + i];
#pragma unroll
            for (int j = 0; j < 8; j++) bv[j] = Rs[kk][tx * 8 + j];
#pragma unroll
            for (int i = 0; i < 4; i++)
#pragma unroll
                for (int j = 0; j < 8; j++)
                    acc[i][j] += a[i] * bv[j];
        }
    }
#pragma unroll
    for (int i = 0; i < 4; i++) {
        int r = i0 + ty * 4 + i;
#pragma unroll
        for (int j = 0; j < 8; j++) {
            int c = j0 + tx * 8 + j;
            double base = (c >= kb && c < kb + NBLK) ? 0.0 : Mb[(long)r * KD + c];
            Mb[(long)r * KD + c] = base - acc[i][j];
        }
    }
}

// ---------- compact a0 (col 0 of A, shifted) and fr (root logits, shifted) with zero pad ----------
__global__ void k_compact(const float* __restrict__ A, const float* __restrict__ fi,
                          double* __restrict__ a0c, double* __restrict__ frc) {
    int idx = blockIdx.x * 256 + threadIdx.x;   // BB*KD
    int b = idx >> 10, i = idx & (KD - 1);
    a0c[idx] = (i < KD - 1) ? (double)A[((long)b << 20) + ((long)(i + 1) << 10)] : 0.0;
    frc[idx] = (i < KD - 1) ? (double)fi[(b << 10) + i + 1] : 0.0;
}

// ---------- w = Tinv @ a0  (wave per row) ----------
__global__ void k_w(const double* __restrict__ Td, const double* __restrict__ a0c, double* __restrict__ wd) {
    int w = (blockIdx.x * 256 + threadIdx.x) >> 6;   // BB*KD waves
    int lane = threadIdx.x & 63;
    int b = w >> 10, r = w & (KD - 1);
    const double* Tb = Td + ((long)b << 20);
    const double* ab = a0c + (b << 10);
    double s = 0.0;
    for (int j = lane; j < KD; j += 64) s += Tb[((long)r << 10) + j] * ab[j];
    for (int off = 32; off; off >>= 1) s += __shfl_down(s, off);
    if (lane == 0) wd[(b << 10) + r] = s;
}

// ---------- v = fr^T @ Tinv  (thread per column, coalesced row reads) ----------
__global__ void k_v(const double* __restrict__ Td, const double* __restrict__ frc, double* __restrict__ vd) {
    int b = blockIdx.y;
    int j = blockIdx.x * 256 + threadIdx.x;
    const double* Tb = Td + ((long)b << 20);
    const double* fb = frc + (b << 10);
    double s = 0.0;
    for (int i = 0; i < KD; i++) s += fb[i] * Tb[((long)i << 10) + j];
    vd[(b << 10) + j] = s;
}

// ---------- s = f0 + v . a0  (wave per batch) ----------
__global__ void k_s(const double* __restrict__ vd, const double* __restrict__ a0c,
                    const float* __restrict__ fi, double* __restrict__ sd) {
    int b = blockIdx.x;
    int lane = threadIdx.x;  // 64
    double s = 0.0;
    for (int j = lane; j < KD; j += 64) s += vd[(b << 10) + j] * a0c[(b << 10) + j];
    for (int off = 32; off; off >>= 1) s += __shfl_down(s, off);
    if (lane == 0) sd[b] = s + (double)fi[b << 10];
}

// ---------- dgv[k] = Linv[k][k], d0[k] = f_k * Linv[k][0] ----------
__global__ void k_dgv(const double* __restrict__ Td, const double* __restrict__ wd,
                      const double* __restrict__ vd, const double* __restrict__ sd,
                      const float* __restrict__ fi, double* __restrict__ dgvd, float* __restrict__ d0) {
    int idx = blockIdx.x * 256 + threadIdx.x;  // BB*KD
    int b = idx >> 10, k = idx & (KD - 1);
    double rs = 1.0 / sd[b];
    if (k == 0) {
        dgvd[idx] = rs;
        d0[idx] = (float)((double)fi[idx] * rs);
    } else {
        int i = k - 1;
        dgvd[idx] = Td[((long)b << 20) + ((long)i << 10) + i] - wd[(b << 10) + i] * vd[(b << 10) + i] * rs;
        d0[idx] = (float)((double)fi[idx] * wd[(b << 10) + i] * rs);
    }
}

// ---------- a_ik in place over A via bordered-inverse algebra ----------
// Linv[k][j]: k=0,j=0: 1/s; k=0,j>=1: -v_{j-1}/s; k>=1,j=0: w_{k-1}/s;
//             k,j>=1: Tinv[k-1][j-1] - w_{k-1} v_{j-1}/s.
// a_ik[j][k] = (k!=0)*A[j,k]*dgv[k] - (j!=0)*A[j,k]*Linv[k][j]
__global__ void k_aik2(float* __restrict__ A, const double* __restrict__ Td,
                       const double* __restrict__ wd, const double* __restrict__ vd,
                       const double* __restrict__ dgvd, const double* __restrict__ sd) {
    __shared__ double Tt[64][65];
    __shared__ double wls[64], vls[64], dgl[64];
    int b = blockIdx.z;
    int k0 = blockIdx.x * 64, j0 = blockIdx.y * 64;
    const double* Tb = Td + ((long)b << 20);
    int t = threadIdx.x;
    for (int i = t; i < 64 * 64; i += 256) {
        int kl = i >> 6, jl = i & 63;
        int kk = k0 + kl - 1, jj = j0 + jl - 1;
        Tt[kl][jl] = (kk >= 0 && jj >= 0) ? Tb[((long)kk << 10) + jj] : 0.0;
    }
    if (t < 64) {
        wls[t] = (k0 + t >= 1) ? wd[(b << 10) + k0 + t - 1] : 0.0;
        vls[t] = (j0 + t >= 1) ? vd[(b << 10) + j0 + t - 1] : 0.0;
        dgl[t] = dgvd[(b << 10) + k0 + t];
    }
    __syncthreads();
    double rs = 1.0 / sd[b];
    int kl = t & 63;
    int k = k0 + kl;
    double dv = dgl[kl], wk = wls[kl];
    for (int pass = 0; pass < 16; pass++) {
        int jl = (t >> 6) + pass * 4;
        int j = j0 + jl;
        long idx = ((long)(b << 10) + j) * KD + k;
        double a = (double)A[idx];
        double out;
        if (k == 0)      out = (j == 0) ? 0.0 : a * vls[jl] * rs;
        else if (j == 0) out = a * dv;
        else             out = a * (dv - Tt[kl][jl] + wk * vls[jl] * rs);
        A[idx] = (float)out;
    }
}

// ---------- a_ki output (transpose + d0 first column) ----------
__global__ void k_aki(const float* __restrict__ A, const float* __restrict__ d0, float* __restrict__ out) {
    __shared__ float T[64][65];
    int b = blockIdx.z;
    int i0 = blockIdx.y * 64;
    int k0 = blockIdx.x * 64;
    const float* Ab = A + (long)b * KD * KD;
    int t = threadIdx.x;
    for (int i = t; i < 64 * 64; i += 256) {
        int r = i / 64, c = i % 64;
        T[r][c] = Ab[(long)(i0 + r) * KD + k0 + c];
    }
    __syncthreads();
    float* ob = out + (long)b * KD * (KD + 1);
    int iloc = t % 64, kl0 = (t / 64) * 16;
    for (int kk = kl0; kk < kl0 + 16; kk++) {
        int kg = k0 + kk;
        ob[(long)kg * (KD + 1) + 1 + i0 + iloc] = T[iloc][kk];
    }
    if (blockIdx.y == 0 && t < 64) {
        int kg = k0 + t;
        ob[(long)kg * (KD + 1)] = d0[b * KD + kg];
    }
}

// ---------- si = a_ik^T @ e_i + d0 (x) exparam ----------
__global__ void k_si(const float* __restrict__ Aik, const float* __restrict__ E,
                     const float* __restrict__ d0, const float* __restrict__ expar,
                     float* __restrict__ Si) {
    __shared__ float As[8][132];
    __shared__ float Bs[8][132];
    int b = blockIdx.z;
    int m0 = blockIdx.x * 128;   // k
    int n0 = blockIdx.y * 128;   // s
    const float* Ab = Aik + (long)b * KD * KD;
    const float* Eb = E + (long)b * KD * SS;
    int t = threadIdx.x, ty = t / 16, tx = t % 16;
    int brow = t / 32, bcol = (t % 32) * 4;
    float acc[8][8] = {};
    for (int j0 = 0; j0 < KD; j0 += 8) {
        float4 av = *(const float4*)&Ab[(long)(j0 + brow) * KD + m0 + bcol];
        float4 bv = *(const float4*)&Eb[(long)(j0 + brow) * SS + n0 + bcol];
        __syncthreads();
        *(float4*)&As[brow][bcol] = av;
        *(float4*)&Bs[brow][bcol] = bv;
        __syncthreads();
#pragma unroll
        for (int kk = 0; kk < 8; kk++) {
            float a[8], b2[8];
            *(float4*)&a[0] = *(const float4*)&As[kk][ty * 8];
            *(float4*)&a[4] = *(const float4*)&As[kk][ty * 8 + 4];
            *(float4*)&b2[0] = *(const float4*)&Bs[kk][tx * 8];
            *(float4*)&b2[4] = *(const float4*)&Bs[kk][tx * 8 + 4];
#pragma unroll
            for (int i = 0; i < 8; i++)
#pragma unroll
                for (int j = 0; j < 8; j++)
                    acc[i][j] += a[i] * b2[j];
        }
    }
#pragma unroll
    for (int i = 0; i < 8; i++) {
        int row = m0 + ty * 8 + i;
#pragma unroll
        for (int j = 0; j < 8; j++) {
            int col = n0 + tx * 8 + j;
            Si[((long)b * KD + row) * SS + col] = acc[i][j] + d0[b * KD + row] * expar[col];
        }
    }
}

// ---------- ci = a_ik @ e_i ----------
__global__ void k_ci(const float* __restrict__ Aik, const float* __restrict__ E, float* __restrict__ Ci) {
    __shared__ float As[8][132];
    __shared__ float Bs[8][132];
    int b = blockIdx.z;
    int m0 = blockIdx.x * 128;
    int n0 = blockIdx.y * 128;
    const float* Ab = Aik + (long)b * KD * KD;
    const float* Eb = E + (long)b * KD * SS;
    int t = threadIdx.x, ty = t / 16, tx = t % 16;
    int arow = t / 2, acol = (t % 2) * 4;
    int brow = t / 32, bcol = (t % 32) * 4;
    float acc[8][8] = {};
    for (int j0 = 0; j0 < KD; j0 += 8) {
        float4 av = *(const float4*)&Ab[(long)(m0 + arow) * KD + j0 + acol];
        float4 bv = *(const float4*)&Eb[(long)(j0 + brow) * SS + n0 + bcol];
        __syncthreads();
        As[acol + 0][arow] = av.x; As[acol + 1][arow] = av.y;
        As[acol + 2][arow] = av.z; As[acol + 3][arow] = av.w;
        *(float4*)&Bs[brow][bcol] = bv;
        __syncthreads();
#pragma unroll
        for (int kk = 0; kk < 8; kk++) {
            float a[8], b2[8];
            *(float4*)&a[0] = *(const float4*)&As[kk][ty * 8];
            *(float4*)&a[4] = *(const float4*)&As[kk][ty * 8 + 4];
            *(float4*)&b2[0] = *(const float4*)&Bs[kk][tx * 8];
            *(float4*)&b2[4] = *(const float4*)&Bs[kk][tx * 8 + 4];
#pragma unroll
            for (int i = 0; i < 8; i++)
#pragma unroll
                for (int j = 0; j < 8; j++)
                    acc[i][j] += a[i] * b2[j];
        }
    }
#pragma unroll
    for (int i = 0; i < 8; i++) {
        int row = m0 + ty * 8 + i;
#pragma unroll
        for (int j = 0; j < 8; j++) {
            int col = n0 + tx * 8 + j;
            Ci[((long)b * KD + row) * SS + col] = acc[i][j];
        }
    }
}

// ---------- r_i = tanh([e,si,ci] @ Wr + br) ----------
__global__ void k_ri(const float* __restrict__ E, const float* __restrict__ Si, const float* __restrict__ Ci,
                     const float* __restrict__ Wr, const float* __restrict__ br, float* __restrict__ out) {
    __shared__ float As[8][132];
    __shared__ float Bs[8][132];
    int m0 = blockIdx.x * 128, n0 = blockIdx.y * 128;
    int t = threadIdx.x, ty = t / 16, tx = t % 16;
    int arow = t / 2, acol = (t % 2) * 4;
    int brow = t / 32, bcol = (t % 32) * 4;
    float acc[8][8] = {};
    const float* srcs[3] = {E, Si, Ci};
    for (int seg = 0; seg < 3; seg++) {
        const float* Sp = srcs[seg];
        for (int k0 = 0; k0 < SS; k0 += 8) {
            float4 av = *(const float4*)&Sp[(long)(m0 + arow) * SS + k0 + acol];
            float4 bv = *(const float4*)&Wr[(long)(seg * SS + k0 + brow) * SS + n0 + bcol];
            __syncthreads();
            As[acol + 0][arow] = av.x; As[acol + 1][arow] = av.y;
            As[acol + 2][arow] = av.z; As[acol + 3][arow] = av.w;
            *(float4*)&Bs[brow][bcol] = bv;
            __syncthreads();
#pragma unroll
            for (int kk = 0; kk < 8; kk++) {
                float a[8], b2[8];
                *(float4*)&a[0] = *(const float4*)&As[kk][ty * 8];
                *(float4*)&a[4] = *(const float4*)&As[kk][ty * 8 + 4];
                *(float4*)&b2[0] = *(const float4*)&Bs[kk][tx * 8];
                *(float4*)&b2[4] = *(const float4*)&Bs[kk][tx * 8 + 4];
#pragma unroll
                for (int i = 0; i < 8; i++)
#pragma unroll
                    for (int j = 0; j < 8; j++)
                        acc[i][j] += a[i] * b2[j];
            }
        }
    }
#pragma unroll
    for (int i = 0; i < 8; i++) {
        int row = m0 + ty * 8 + i;
#pragma unroll
        for (int j = 0; j < 8; j++) {
            int col = n0 + tx * 8 + j;
            out[(long)row * SS + col] = tanhf(acc[i][j] + br[col]);
        }
    }
}

extern "C" void kernel_launch(void* const* d_in, const int* in_sizes, int n_in,
                              void* d_out, int out_size, void* d_ws, size_t ws_size,
                              hipStream_t stream) {
    const float* x     = (const float*)d_in[0];
    const float* Wp_w  = (const float*)d_in[1];
    const float* Wp_b  = (const float*)d_in[2];
    const float* Wc_w  = (const float*)d_in[3];
    const float* Wc_b  = (const float*)d_in[4];
    const float* fi_w  = (const float*)d_in[5];
    const float* Wa_w  = (const float*)d_in[6];
    const float* expar = (const float*)d_in[7];
    const float* Wr_w  = (const float*)d_in[8];
    const float* Wr_b  = (const float*)d_in[9];

    float* ws = (float*)d_ws;
    // Region R (offset 23,068,672, span 33,554,432 f32 = 128 MB) is time-multiplexed:
    // early {di/tt, uj, uk}; mid: Td (fp64 padded T matrix -> Tinv); late: {si, ci}.
    float*  A    = ws;                               // 16,777,216 f32 (S -> A -> a_ik)
    float*  ei   = ws + 16777216;                    //  6,291,456 f32
    float*  R    = ws + 23068672;
    float*  di   = R;
    float*  uj   = R + 6291456;
    float*  uk   = R + 12582912;
    float*  tt   = di;
    double* Td   = (double*)R;                       // 16,777,216 doubles = 128 MB
    float*  sbuf = R;                                // after Td dead
    float*  cbuf = R + 6291456;
    double* Ftd  = (double*)(ws + 56623104);         // 1,048,576 doubles = 8 MB
    float*  g    = ws + 58720256;                    // 16,384
    float*  mcol = ws + 58736640;                    // 16,384
    float*  fi   = ws + 58753024;                    // 16,384
    float*  d0   = ws + 58769408;                    // 16,384
    double* csd  = (double*)(ws + 58785792);         // 16,384 doubles
    double* wd   = (double*)(ws + 58818560);         // 16,384 doubles
    double* vd   = (double*)(ws + 58851328);         // 16,384 doubles
    double* dgvd = (double*)(ws + 58884096);         // 16,384 doubles
    double* a0c  = (double*)(ws + 58916864);         // 16,384 doubles
    double* frc  = (double*)(ws + 58949632);         // 16,384 doubles
    double* sd   = (double*)(ws + 58982400);         // 16 doubles; end ~236 MB

    float* r_out   = (float*)d_out;
    float* aki_out = r_out + (long)BB * KD * SS;

    k_prep<<<BB * KD * SS / 256, 256, 0, stream>>>(x, di, ei);
    k_gemm_nn<true, true><<<dim3(128, 3), 256, 0, stream>>>(di, Wp_w, Wp_b, uj, BB * KD, SS, SS);
    k_gemm_nn<true, true><<<dim3(128, 3), 256, 0, stream>>>(di, Wc_w, Wc_b, uk, BB * KD, SS, SS);
    k_firaw<<<BB * KD / 4, 256, 0, stream>>>(di, fi_w, g);
    k_gemm_nn<false, false><<<dim3(128, 3), 256, 0, stream>>>(uj, Wa_w, nullptr, tt, BB * KD, SS, SS);
    k_fjk<<<dim3(8, 8, BB), 256, 0, stream>>>(tt, uk, A);
    k_colmax<<<BB * KD / 256, 256, 0, stream>>>(A, g, mcol);
    k_expA<<<BB * KD * KD / 256, 256, 0, stream>>>(A, mcol);
    k_fi2<<<BB * KD / 256, 256, 0, stream>>>(g, mcol, fi);
    k_colsum_d<<<BB * KD / 256, 256, 0, stream>>>(A, csd);
    k_buildT<<<BB * KD * KD / 256, 256, 0, stream>>>(A, csd, Td);

    for (int s = 0; s < KD / NBLK; s++) {
        int kb = s * NBLK;
        k_diag_d<<<BB, 256, 0, stream>>>(Td, kb);
        k_savecol_d<<<BB * KD * NBLK / 256, 256, 0, stream>>>(Td, Ftd, kb);
        k_rowcol_d<<<dim3(15, BB), 256, 0, stream>>>(Td, kb);
        k_elim_d<<<dim3(8, 16, BB), 256, 0, stream>>>(Td, Ftd, kb);
    }

    k_compact<<<BB * KD / 256, 256, 0, stream>>>(A, fi, a0c, frc);
    k_w<<<BB * KD / 4, 256, 0, stream>>>(Td, a0c, wd);
    k_v<<<dim3(4, BB), 256, 0, stream>>>(Td, frc, vd);
    k_s<<<BB, 64, 0, stream>>>(vd, a0c, fi, sd);
    k_dgv<<<BB * KD / 256, 256, 0, stream>>>(Td, wd, vd, sd, fi, dgvd, d0);
    k_aik2<<<dim3(16, 16, BB), 256, 0, stream>>>(A, Td, wd, vd, dgvd, sd);
    k_aki<<<dim3(16, 16, BB), 256, 0, stream>>>(A, d0, aki_out);
    k_si<<<dim3(8, 3, BB), 256, 0, stream>>>(A, ei, d0, expar, sbuf);
    k_ci<<<dim3(8, 3, BB), 256, 0, stream>>>(A, ei, cbuf);
    k_ri<<<dim3(128, 3), 256, 0, stream>>>(ei, sbuf, cbuf, Wr_w, Wr_b, r_out);
}

// Round 5
// 4684.737 us; speedup vs baseline: 1.2546x; 1.2546x over previous
//
#include <hip/hip_runtime.h>

#define BB 16
#define KD 1024
#define DD 768
#define SS 384
#define HH 192
#define NBLK 64

// ================= common 128x128xBK16 fp32 GEMM micro-core =================
// 256 threads, 8x8 acc per thread, rows {ty*4, 64+ty*4}, cols {tx*4, 64+tx*4}.
// All LDS reads <=2-way bank aliasing (free on CDNA4).
__device__ __forceinline__ void mac16(float (&acc)[8][8], const float (*As)[132], const float (*Bs)[132],
                                      int ty, int tx) {
#pragma unroll
    for (int kk = 0; kk < 16; kk++) {
        float a[8], b[8];
        *(float4*)&a[0] = *(const float4*)&As[kk][ty * 4];
        *(float4*)&a[4] = *(const float4*)&As[kk][64 + ty * 4];
        *(float4*)&b[0] = *(const float4*)&Bs[kk][tx * 4];
        *(float4*)&b[4] = *(const float4*)&Bs[kk][64 + tx * 4];
#pragma unroll
        for (int i = 0; i < 8; i++)
#pragma unroll
            for (int j = 0; j < 8; j++)
                acc[i][j] += a[i] * b[j];
    }
}

// transpose-store an A-style tile (row-major MxK source chunk) into As[k][m]
__device__ __forceinline__ void storeA_t(float (*As)[132], const float4& v0, const float4& v1,
                                         int la_r, int la_c) {
    As[la_c + 0][la_r] = v0.x; As[la_c + 1][la_r] = v0.y;
    As[la_c + 2][la_r] = v0.z; As[la_c + 3][la_r] = v0.w;
    As[la_c + 0][64 + la_r] = v1.x; As[la_c + 1][64 + la_r] = v1.y;
    As[la_c + 2][64 + la_r] = v1.z; As[la_c + 3][64 + la_r] = v1.w;
}

// ---------- split x into e_i / d_i ----------
__global__ void k_prep(const float* __restrict__ x, float* __restrict__ di, float* __restrict__ ei) {
    int idx = blockIdx.x * 256 + threadIdx.x;       // over BB*KD*SS
    int s = idx % SS;
    long bk = idx / SS;
    const float* xr = x + bk * DD;
    ei[idx] = xr[s < HH ? s : s + HH];
    di[idx] = xr[s < HH ? s + HH : s + 2 * HH];
}

// ---------- generic fp32 NN GEMM: C[M,N] = act(A[M,Kd] @ B[Kd,N] + bias) ----------
template<bool BIAS, bool TANH>
__global__ __launch_bounds__(256, 2)
void k_gemm16(const float* __restrict__ A, const float* __restrict__ Bw,
              const float* __restrict__ bias, float* __restrict__ C,
              int M, int N, int Kd) {
    __shared__ float As[16][132];
    __shared__ float Bs[16][132];
    int m0 = blockIdx.x * 128, n0 = blockIdx.y * 128;
    int t = threadIdx.x;
    int ty = t / 16, tx = t % 16;
    int la_r = t / 4, la_c = (t % 4) * 4;
    int lb_r = t / 16, lb_c = (t % 16) * 4;
    float acc[8][8] = {};
    for (int k0 = 0; k0 < Kd; k0 += 16) {
        float4 a0 = *(const float4*)&A[(long)(m0 + la_r) * Kd + k0 + la_c];
        float4 a1 = *(const float4*)&A[(long)(m0 + 64 + la_r) * Kd + k0 + la_c];
        float4 b0 = *(const float4*)&Bw[(long)(k0 + lb_r) * N + n0 + lb_c];
        float4 b1 = *(const float4*)&Bw[(long)(k0 + lb_r) * N + n0 + 64 + lb_c];
        __syncthreads();
        storeA_t(As, a0, a1, la_r, la_c);
        *(float4*)&Bs[lb_r][lb_c] = b0;
        *(float4*)&Bs[lb_r][64 + lb_c] = b1;
        __syncthreads();
        mac16(acc, As, Bs, ty, tx);
    }
#pragma unroll
    for (int i = 0; i < 8; i++) {
        int row = m0 + (i < 4 ? ty * 4 + i : 64 + ty * 4 + i - 4);
        float4 o0, o1;
        float* p0 = &o0.x; float* p1 = &o1.x;
#pragma unroll
        for (int j = 0; j < 4; j++) {
            float v = acc[i][j];
            if (BIAS) v += bias[n0 + tx * 4 + j];
            if (TANH) v = tanhf(v);
            p0[j] = v;
            float w = acc[i][j + 4];
            if (BIAS) w += bias[n0 + 64 + tx * 4 + j];
            if (TANH) w = tanhf(w);
            p1[j] = w;
        }
        *(float4*)&C[(long)row * N + n0 + tx * 4] = o0;
        *(float4*)&C[(long)row * N + n0 + 64 + tx * 4] = o1;
    }
}

// ---------- batched NT GEMM: S[b,j,k] = sum_s T[b,j,s]*Uk[b,k,s]  (raw scores) ----------
__global__ __launch_bounds__(256, 2)
void k_fjk16(const float* __restrict__ T, const float* __restrict__ Uk, float* __restrict__ Sout) {
    __shared__ float As[16][132];
    __shared__ float Bs[16][132];
    int b = blockIdx.z;
    const float* Ab = T + (long)b * KD * SS;
    const float* Bb = Uk + (long)b * KD * SS;
    int m0 = blockIdx.x * 128, n0 = blockIdx.y * 128;
    int t = threadIdx.x;
    int ty = t / 16, tx = t % 16;
    int la_r = t / 4, la_c = (t % 4) * 4;
    float acc[8][8] = {};
    for (int k0 = 0; k0 < SS; k0 += 16) {
        float4 a0 = *(const float4*)&Ab[(long)(m0 + la_r) * SS + k0 + la_c];
        float4 a1 = *(const float4*)&Ab[(long)(m0 + 64 + la_r) * SS + k0 + la_c];
        float4 b0 = *(const float4*)&Bb[(long)(n0 + la_r) * SS + k0 + la_c];
        float4 b1 = *(const float4*)&Bb[(long)(n0 + 64 + la_r) * SS + k0 + la_c];
        __syncthreads();
        storeA_t(As, a0, a1, la_r, la_c);
        storeA_t(Bs, b0, b1, la_r, la_c);
        __syncthreads();
        mac16(acc, As, Bs, ty, tx);
    }
#pragma unroll
    for (int i = 0; i < 8; i++) {
        int row = m0 + (i < 4 ? ty * 4 + i : 64 + ty * 4 + i - 4);
        *(float4*)&Sout[((long)b * KD + row) * KD + n0 + tx * 4] = *(float4*)&acc[i][0];
        *(float4*)&Sout[((long)b * KD + row) * KD + n0 + 64 + tx * 4] = *(float4*)&acc[i][4];
    }
}

// ---------- raw root logit g = d_i . fi_w ----------
__global__ void k_firaw(const float* __restrict__ di, const float* __restrict__ fiw, float* __restrict__ g) {
    int w = (blockIdx.x * 256 + threadIdx.x) / 64;
    int lane = threadIdx.x % 64;
    if (w >= BB * KD) return;
    const float* dr = di + (long)w * SS;
    float s = 0.f;
    for (int i = lane; i < SS; i += 64) s += dr[i] * fiw[i];
    for (int off = 32; off; off >>= 1) s += __shfl_down(s, off);
    if (lane == 0) g[w] = s;
}

// ---------- per-column max m[b,k] = max(g[b,k], max_{j!=k} S[b,j,k]) ----------
__global__ void k_colmax(const float* __restrict__ S, const float* __restrict__ g, float* __restrict__ mcol) {
    int idx = blockIdx.x * 256 + threadIdx.x;   // BB*KD
    int b = idx >> 10, k = idx & (KD - 1);
    const float* Sb = S + (long)b * KD * KD;
    float m = g[idx];
    for (int j = 0; j < KD; j++) {
        float v = Sb[(long)j * KD + k];
        m = fmaxf(m, (j == k) ? -3.4e38f : v);
    }
    mcol[idx] = m;
}

// ---------- A = exp(S - m_col), diag zeroed (in place) ----------
__global__ void k_expA(float* __restrict__ S, const float* __restrict__ mcol) {
    int idx = blockIdx.x * 256 + threadIdx.x;   // BB*KD*KD
    int k = idx & (KD - 1);
    int j = (idx >> 10) & (KD - 1);
    int b = idx >> 20;
    S[idx] = (j == k) ? 0.f : expf(S[idx] - mcol[(b << 10) + k]);
}

// ---------- fi = exp(g - m_col) ----------
__global__ void k_fi2(const float* __restrict__ g, const float* __restrict__ mcol, float* __restrict__ fi) {
    int idx = blockIdx.x * 256 + threadIdx.x;   // BB*KD
    fi[idx] = expf(g[idx] - mcol[idx]);
}

// ---------- column sums (fp64) ----------
__global__ void k_colsum_d(const float* __restrict__ A, double* __restrict__ csd) {
    int idx = blockIdx.x * 256 + threadIdx.x;   // BB*KD
    int b = idx >> 10, k = idx & (KD - 1);
    const float* Ab = A + (long)b * KD * KD;
    double s = 0.0;
    for (int j = 0; j < KD; j++) s += (double)Ab[(long)j * KD + k];
    csd[idx] = s;
}

// ---------- build padded T~ (fp64): T[i][j] = L[1+i][1+j] for i,j<1023; identity pad at 1023 ----------
__global__ void k_buildT(const float* __restrict__ A, const double* __restrict__ csd, double* __restrict__ Td) {
    long idx = (long)blockIdx.x * 256 + threadIdx.x;  // BB*KD*KD
    int j = idx & (KD - 1);
    int i = (int)(idx >> 10) & (KD - 1);
    int b = (int)(idx >> 20);
    double v;
    if (i == KD - 1 || j == KD - 1) v = (i == j) ? 1.0 : 0.0;
    else if (i == j) v = csd[(b << 10) + j + 1];
    else v = -(double)A[((long)b << 20) + ((long)(i + 1) << 10) + (j + 1)];
    Td[idx] = v;
}

// ---------- GJ step (fp64): invert diagonal 64x64 block in LDS ----------
__global__ __launch_bounds__(256)
void k_diag_d(double* __restrict__ M, int kb) {
    __shared__ double P[NBLK][NBLK + 1];
    __shared__ double rowbuf[NBLK];
    int b = blockIdx.x;
    double* Mb = M + (long)b * KD * KD;
    int t = threadIdx.x;
    for (int i = t; i < NBLK * NBLK; i += 256)
        P[i / NBLK][i % NBLK] = Mb[(long)(kb + i / NBLK) * KD + kb + i % NBLK];
    __syncthreads();
    int mi = t & 63;
    int c0 = (t >> 6) * 16;
    for (int kk = 0; kk < NBLK; kk++) {
        double p = 1.0 / P[kk][kk];
        double F = P[mi][kk];
        if (t < 64) rowbuf[t] = P[kk][t] * p;
        __syncthreads();
        if (mi == kk) {
            for (int c = c0; c < c0 + 16; c++)
                P[mi][c] = (c == kk) ? p : rowbuf[c];
        } else {
            for (int c = c0; c < c0 + 16; c++)
                P[mi][c] = (c == kk) ? (-F * p) : (P[mi][c] - F * rowbuf[c]);
        }
        __syncthreads();
    }
    for (int i = t; i < NBLK * NBLK; i += 256)
        Mb[(long)(kb + i / NBLK) * KD + kb + i % NBLK] = P[i / NBLK][i % NBLK];
}

// ---------- GJ step (fp64): save old pivot-column block ----------
__global__ void k_savecol_d(const double* __restrict__ M, double* __restrict__ Ft, int kb) {
    int idx = blockIdx.x * 256 + threadIdx.x;     // BB*KD*NBLK
    int c = idx % NBLK;
    int rk = idx / NBLK;
    int r = rk % KD, b = rk / KD;
    Ft[idx] = M[((long)b * KD + r) * KD + kb + c];
}

// ---------- GJ step (fp64): pivot block-row update  M[k,j] = Dinv @ M[k,j], j != ktile ----------
__global__ __launch_bounds__(256)
void k_rowcol_d(double* __restrict__ M, int kb) {
    __shared__ double Ps[NBLK][NBLK + 1];   // Ps[col][row] = Dinv[row][col]
    __shared__ double Ts[16][NBLK + 2];
    int b = blockIdx.y;
    int jt = blockIdx.x;
    int kt = kb / NBLK;
    if (jt >= kt) jt++;                    // grid.x = 15, skip diagonal tile
    int j0 = jt * NBLK;
    double* Mb = M + (long)b * KD * KD;
    int t = threadIdx.x;
    for (int i = t; i < NBLK * NBLK; i += 256) {
        int r = i / NBLK, c = i % NBLK;
        Ps[c][r] = Mb[(long)(kb + r) * KD + kb + c];
    }
    int ty = t >> 4, tx = t & 15;
    double acc[4][4] = {};
    for (int kc = 0; kc < NBLK; kc += 16) {
        __syncthreads();
        for (int i = t; i < 16 * NBLK; i += 256) {
            int r = i / NBLK, c = i % NBLK;
            Ts[r][c] = Mb[(long)(kb + kc + r) * KD + j0 + c];
        }
        __syncthreads();
#pragma unroll
        for (int kk = 0; kk < 16; kk++) {
            double a[4], bv[4];
#pragma unroll
            for (int i = 0; i < 4; i++) a[i] = Ps[kc + kk][ty * 4 + i];
#pragma unroll
            for (int j = 0; j < 4; j++) bv[j] = Ts[kk][tx * 4 + j];
#pragma unroll
            for (int i = 0; i < 4; i++)
#pragma unroll
                for (int j = 0; j < 4; j++)
                    acc[i][j] += a[i] * bv[j];
        }
    }
#pragma unroll
    for (int i = 0; i < 4; i++)
#pragma unroll
        for (int j = 0; j < 4; j++)
            Mb[(long)(kb + ty * 4 + i) * KD + j0 + tx * 4 + j] = acc[i][j];
}

// ---------- GJ step (fp64): trailing elimination + pivot-column update ----------
// cols split {p*32+tx*2}: conflict-free LDS reads, coalesced double2 global R/W.
__global__ __launch_bounds__(256, 2)
void k_elim_d(double* __restrict__ M, const double* __restrict__ Ft, int kb) {
    __shared__ double Fs[16][NBLK + 2];    // Fs[kcol][row]
    __shared__ double Rs[16][132];         // Rs[krow][col]
    int b = blockIdx.z;
    int it = blockIdx.y;
    int kt = kb / NBLK;
    if (it == kt) return;
    int i0 = it * NBLK;
    int j0 = blockIdx.x * 128;
    double* Mb = M + (long)b * KD * KD;
    const double* Fb = Ft + ((long)b * KD + i0) * NBLK;
    const double* Rrow = Mb + (long)kb * KD;
    int t = threadIdx.x, ty = t >> 4, tx = t & 15;
    double acc[4][8] = {};
    for (int kc = 0; kc < NBLK; kc += 16) {
        __syncthreads();
        for (int i = t; i < 16 * NBLK; i += 256) {
            int r = i >> 4, c = i & 15;
            Fs[c][r] = Fb[(long)r * NBLK + kc + c];
        }
        for (int i = t; i < 16 * 128; i += 256) {
            int r = i >> 7, c = i & 127;
            Rs[r][c] = Rrow[(long)(kc + r) * KD + j0 + c];
        }
        __syncthreads();
#pragma unroll
        for (int kk = 0; kk < 16; kk++) {
            double a[4], bv[8];
#pragma unroll
            for (int i = 0; i < 4; i++) a[i] = Fs[kk][ty * 4 + i];
#pragma unroll
            for (int p = 0; p < 4; p++) {
                bv[p * 2 + 0] = Rs[kk][p * 32 + tx * 2 + 0];
                bv[p * 2 + 1] = Rs[kk][p * 32 + tx * 2 + 1];
            }
#pragma unroll
            for (int i = 0; i < 4; i++)
#pragma unroll
                for (int j = 0; j < 8; j++)
                    acc[i][j] += a[i] * bv[j];
        }
    }
#pragma unroll
    for (int i = 0; i < 4; i++) {
        int r = i0 + ty * 4 + i;
#pragma unroll
        for (int p = 0; p < 4; p++) {
            int c = j0 + p * 32 + tx * 2;
            bool piv = (c >= kb && c < kb + NBLK);
            double b0 = piv ? 0.0 : Mb[(long)r * KD + c];
            double b1 = piv ? 0.0 : Mb[(long)r * KD + c + 1];
            Mb[(long)r * KD + c]     = b0 - acc[i][p * 2 + 0];
            Mb[(long)r * KD + c + 1] = b1 - acc[i][p * 2 + 1];
        }
    }
}

// ---------- compact a0 (col 0 of A, shifted) and fr (root logits, shifted) with zero pad ----------
__global__ void k_compact(const float* __restrict__ A, const float* __restrict__ fi,
                          double* __restrict__ a0c, double* __restrict__ frc) {
    int idx = blockIdx.x * 256 + threadIdx.x;   // BB*KD
    int b = idx >> 10, i = idx & (KD - 1);
    a0c[idx] = (i < KD - 1) ? (double)A[((long)b << 20) + ((long)(i + 1) << 10)] : 0.0;
    frc[idx] = (i < KD - 1) ? (double)fi[(b << 10) + i + 1] : 0.0;
}

// ---------- w = Tinv @ a0  (wave per row) ----------
__global__ void k_w(const double* __restrict__ Td, const double* __restrict__ a0c, double* __restrict__ wd) {
    int w = (blockIdx.x * 256 + threadIdx.x) >> 6;   // BB*KD waves
    int lane = threadIdx.x & 63;
    int b = w >> 10, r = w & (KD - 1);
    const double* Tb = Td + ((long)b << 20);
    const double* ab = a0c + (b << 10);
    double s = 0.0;
    for (int j = lane; j < KD; j += 64) s += Tb[((long)r << 10) + j] * ab[j];
    for (int off = 32; off; off >>= 1) s += __shfl_down(s, off);
    if (lane == 0) wd[(b << 10) + r] = s;
}

// ---------- v = fr^T @ Tinv  (thread per column, coalesced row reads) ----------
__global__ void k_v(const double* __restrict__ Td, const double* __restrict__ frc, double* __restrict__ vd) {
    int b = blockIdx.y;
    int j = blockIdx.x * 256 + threadIdx.x;
    const double* Tb = Td + ((long)b << 20);
    const double* fb = frc + (b << 10);
    double s = 0.0;
    for (int i = 0; i < KD; i++) s += fb[i] * Tb[((long)i << 10) + j];
    vd[(b << 10) + j] = s;
}

// ---------- s = f0 + v . a0  (wave per batch) ----------
__global__ void k_s(const double* __restrict__ vd, const double* __restrict__ a0c,
                    const float* __restrict__ fi, double* __restrict__ sd) {
    int b = blockIdx.x;
    int lane = threadIdx.x;  // 64
    double s = 0.0;
    for (int j = lane; j < KD; j += 64) s += vd[(b << 10) + j] * a0c[(b << 10) + j];
    for (int off = 32; off; off >>= 1) s += __shfl_down(s, off);
    if (lane == 0) sd[b] = s + (double)fi[b << 10];
}

// ---------- dgv[k] = Linv[k][k], d0[k] = f_k * Linv[k][0] ----------
__global__ void k_dgv(const double* __restrict__ Td, const double* __restrict__ wd,
                      const double* __restrict__ vd, const double* __restrict__ sd,
                      const float* __restrict__ fi, double* __restrict__ dgvd, float* __restrict__ d0) {
    int idx = blockIdx.x * 256 + threadIdx.x;  // BB*KD
    int b = idx >> 10, k = idx & (KD - 1);
    double rs = 1.0 / sd[b];
    if (k == 0) {
        dgvd[idx] = rs;
        d0[idx] = (float)((double)fi[idx] * rs);
    } else {
        int i = k - 1;
        dgvd[idx] = Td[((long)b << 20) + ((long)i << 10) + i] - wd[(b << 10) + i] * vd[(b << 10) + i] * rs;
        d0[idx] = (float)((double)fi[idx] * wd[(b << 10) + i] * rs);
    }
}

// ---------- a_ik in place over A via bordered-inverse algebra ----------
__global__ __launch_bounds__(256)
void k_aik2(float* __restrict__ A, const double* __restrict__ Td,
            const double* __restrict__ wd, const double* __restrict__ vd,
            const double* __restrict__ dgvd, const double* __restrict__ sd) {
    __shared__ double Tt[64][65];
    __shared__ double wls[64], vls[64], dgl[64];
    int b = blockIdx.z;
    int k0 = blockIdx.x * 64, j0 = blockIdx.y * 64;
    const double* Tb = Td + ((long)b << 20);
    int t = threadIdx.x;
    for (int i = t; i < 64 * 64; i += 256) {
        int kl = i >> 6, jl = i & 63;
        int kk = k0 + kl - 1, jj = j0 + jl - 1;
        Tt[kl][jl] = (kk >= 0 && jj >= 0) ? Tb[((long)kk << 10) + jj] : 0.0;
    }
    if (t < 64) {
        wls[t] = (k0 + t >= 1) ? wd[(b << 10) + k0 + t - 1] : 0.0;
        vls[t] = (j0 + t >= 1) ? vd[(b << 10) + j0 + t - 1] : 0.0;
        dgl[t] = dgvd[(b << 10) + k0 + t];
    }
    __syncthreads();
    double rs = 1.0 / sd[b];
    int kl = t & 63;
    int k = k0 + kl;
    double dv = dgl[kl], wk = wls[kl];
    for (int pass = 0; pass < 16; pass++) {
        int jl = (t >> 6) + pass * 4;
        int j = j0 + jl;
        long idx = ((long)(b << 10) + j) * KD + k;
        double a = (double)A[idx];
        double out;
        if (k == 0)      out = (j == 0) ? 0.0 : a * vls[jl] * rs;
        else if (j == 0) out = a * dv;
        else             out = a * (dv - Tt[kl][jl] + wk * vls[jl] * rs);
        A[idx] = (float)out;
    }
}

// ---------- a_ki output (transpose + d0 first column) ----------
__global__ void k_aki(const float* __restrict__ A, const float* __restrict__ d0, float* __restrict__ out) {
    __shared__ float T[64][65];
    int b = blockIdx.z;
    int i0 = blockIdx.y * 64;
    int k0 = blockIdx.x * 64;
    const float* Ab = A + (long)b * KD * KD;
    int t = threadIdx.x;
    for (int i = t; i < 64 * 64; i += 256) {
        int r = i / 64, c = i % 64;
        T[r][c] = Ab[(long)(i0 + r) * KD + k0 + c];
    }
    __syncthreads();
    float* ob = out + (long)b * KD * (KD + 1);
    int iloc = t % 64, kl0 = (t / 64) * 16;
    for (int kk = kl0; kk < kl0 + 16; kk++) {
        int kg = k0 + kk;
        ob[(long)kg * (KD + 1) + 1 + i0 + iloc] = T[iloc][kk];
    }
    if (blockIdx.y == 0 && t < 64) {
        int kg = k0 + t;
        ob[(long)kg * (KD + 1)] = d0[b * KD + kg];
    }
}

// ---------- si = a_ik^T @ e_i + d0 (x) exparam ----------
__global__ __launch_bounds__(256, 2)
void k_si16(const float* __restrict__ Aik, const float* __restrict__ E,
            const float* __restrict__ d0, const float* __restrict__ expar,
            float* __restrict__ Si) {
    __shared__ float As[16][132];
    __shared__ float Bs[16][132];
    int b = blockIdx.z;
    int m0 = blockIdx.x * 128;   // k
    int n0 = blockIdx.y * 128;   // s
    const float* Ab = Aik + (long)b * KD * KD;
    const float* Eb = E + (long)b * KD * SS;
    int t = threadIdx.x, ty = t / 16, tx = t % 16;
    int lb_r = t / 16, lb_c = (t % 16) * 4;
    float acc[8][8] = {};
    for (int j0 = 0; j0 < KD; j0 += 16) {
        float4 a0 = *(const float4*)&Ab[(long)(j0 + lb_r) * KD + m0 + lb_c];
        float4 a1 = *(const float4*)&Ab[(long)(j0 + lb_r) * KD + m0 + 64 + lb_c];
        float4 b0 = *(const float4*)&Eb[(long)(j0 + lb_r) * SS + n0 + lb_c];
        float4 b1 = *(const float4*)&Eb[(long)(j0 + lb_r) * SS + n0 + 64 + lb_c];
        __syncthreads();
        *(float4*)&As[lb_r][lb_c] = a0;
        *(float4*)&As[lb_r][64 + lb_c] = a1;
        *(float4*)&Bs[lb_r][lb_c] = b0;
        *(float4*)&Bs[lb_r][64 + lb_c] = b1;
        __syncthreads();
        mac16(acc, As, Bs, ty, tx);
    }
#pragma unroll
    for (int i = 0; i < 8; i++) {
        int row = m0 + (i < 4 ? ty * 4 + i : 64 + ty * 4 + i - 4);
        float dr = d0[b * KD + row];
        float4 o0, o1;
        float* p0 = &o0.x; float* p1 = &o1.x;
#pragma unroll
        for (int j = 0; j < 4; j++) {
            p0[j] = acc[i][j] + dr * expar[n0 + tx * 4 + j];
            p1[j] = acc[i][j + 4] + dr * expar[n0 + 64 + tx * 4 + j];
        }
        *(float4*)&Si[((long)b * KD + row) * SS + n0 + tx * 4] = o0;
        *(float4*)&Si[((long)b * KD + row) * SS + n0 + 64 + tx * 4] = o1;
    }
}

// ---------- ci = a_ik @ e_i ----------
__global__ __launch_bounds__(256, 2)
void k_ci16(const float* __restrict__ Aik, const float* __restrict__ E, float* __restrict__ Ci) {
    __shared__ float As[16][132];
    __shared__ float Bs[16][132];
    int b = blockIdx.z;
    int m0 = blockIdx.x * 128;
    int n0 = blockIdx.y * 128;
    const float* Ab = Aik + (long)b * KD * KD;
    const float* Eb = E + (long)b * KD * SS;
    int t = threadIdx.x, ty = t / 16, tx = t % 16;
    int la_r = t / 4, la_c = (t % 4) * 4;
    int lb_r = t / 16, lb_c = (t % 16) * 4;
    float acc[8][8] = {};
    for (int k0 = 0; k0 < KD; k0 += 16) {
        float4 a0 = *(const float4*)&Ab[(long)(m0 + la_r) * KD + k0 + la_c];
        float4 a1 = *(const float4*)&Ab[(long)(m0 + 64 + la_r) * KD + k0 + la_c];
        float4 b0 = *(const float4*)&Eb[(long)(k0 + lb_r) * SS + n0 + lb_c];
        float4 b1 = *(const float4*)&Eb[(long)(k0 + lb_r) * SS + n0 + 64 + lb_c];
        __syncthreads();
        storeA_t(As, a0, a1, la_r, la_c);
        *(float4*)&Bs[lb_r][lb_c] = b0;
        *(float4*)&Bs[lb_r][64 + lb_c] = b1;
        __syncthreads();
        mac16(acc, As, Bs, ty, tx);
    }
#pragma unroll
    for (int i = 0; i < 8; i++) {
        int row = m0 + (i < 4 ? ty * 4 + i : 64 + ty * 4 + i - 4);
        *(float4*)&Ci[((long)b * KD + row) * SS + n0 + tx * 4] = *(float4*)&acc[i][0];
        *(float4*)&Ci[((long)b * KD + row) * SS + n0 + 64 + tx * 4] = *(float4*)&acc[i][4];
    }
}

// ---------- r_i = tanh([e,si,ci] @ Wr + br) ----------
__global__ __launch_bounds__(256, 2)
void k_ri16(const float* __restrict__ E, const float* __restrict__ Si, const float* __restrict__ Ci,
            const float* __restrict__ Wr, const float* __restrict__ br, float* __restrict__ out) {
    __shared__ float As[16][132];
    __shared__ float Bs[16][132];
    int m0 = blockIdx.x * 128, n0 = blockIdx.y * 128;
    int t = threadIdx.x, ty = t / 16, tx = t % 16;
    int la_r = t / 4, la_c = (t % 4) * 4;
    int lb_r = t / 16, lb_c = (t % 16) * 4;
    float acc[8][8] = {};
    const float* srcs[3] = {E, Si, Ci};
    for (int seg = 0; seg < 3; seg++) {
        const float* Sp = srcs[seg];
        for (int k0 = 0; k0 < SS; k0 += 16) {
            float4 a0 = *(const float4*)&Sp[(long)(m0 + la_r) * SS + k0 + la_c];
            float4 a1 = *(const float4*)&Sp[(long)(m0 + 64 + la_r) * SS + k0 + la_c];
            float4 b0 = *(const float4*)&Wr[(long)(seg * SS + k0 + lb_r) * SS + n0 + lb_c];
            float4 b1 = *(const float4*)&Wr[(long)(seg * SS + k0 + lb_r) * SS + n0 + 64 + lb_c];
            __syncthreads();
            storeA_t(As, a0, a1, la_r, la_c);
            *(float4*)&Bs[lb_r][lb_c] = b0;
            *(float4*)&Bs[lb_r][64 + lb_c] = b1;
            __syncthreads();
            mac16(acc, As, Bs, ty, tx);
        }
    }
#pragma unroll
    for (int i = 0; i < 8; i++) {
        int row = m0 + (i < 4 ? ty * 4 + i : 64 + ty * 4 + i - 4);
        float4 o0, o1;
        float* p0 = &o0.x; float* p1 = &o1.x;
#pragma unroll
        for (int j = 0; j < 4; j++) {
            p0[j] = tanhf(acc[i][j] + br[n0 + tx * 4 + j]);
            p1[j] = tanhf(acc[i][j + 4] + br[n0 + 64 + tx * 4 + j]);
        }
        *(float4*)&out[(long)row * SS + n0 + tx * 4] = o0;
        *(float4*)&out[(long)row * SS + n0 + 64 + tx * 4] = o1;
    }
}

extern "C" void kernel_launch(void* const* d_in, const int* in_sizes, int n_in,
                              void* d_out, int out_size, void* d_ws, size_t ws_size,
                              hipStream_t stream) {
    const float* x     = (const float*)d_in[0];
    const float* Wp_w  = (const float*)d_in[1];
    const float* Wp_b  = (const float*)d_in[2];
    const float* Wc_w  = (const float*)d_in[3];
    const float* Wc_b  = (const float*)d_in[4];
    const float* fi_w  = (const float*)d_in[5];
    const float* Wa_w  = (const float*)d_in[6];
    const float* expar = (const float*)d_in[7];
    const float* Wr_w  = (const float*)d_in[8];
    const float* Wr_b  = (const float*)d_in[9];

    float* ws = (float*)d_ws;
    // Region R (offset 23,068,672, span 33,554,432 f32 = 128 MB) is time-multiplexed:
    // early {di/tt, uj, uk}; mid: Td (fp64 padded T matrix -> Tinv); late: {si, ci}.
    float*  A    = ws;                               // 16,777,216 f32 (S -> A -> a_ik)
    float*  ei   = ws + 16777216;                    //  6,291,456 f32
    float*  R    = ws + 23068672;
    float*  di   = R;
    float*  uj   = R + 6291456;
    float*  uk   = R + 12582912;
    float*  tt   = di;
    double* Td   = (double*)R;                       // 16,777,216 doubles = 128 MB
    float*  sbuf = R;                                // after Td dead
    float*  cbuf = R + 6291456;
    double* Ftd  = (double*)(ws + 56623104);         // 1,048,576 doubles = 8 MB
    float*  g    = ws + 58720256;                    // 16,384
    float*  mcol = ws + 58736640;                    // 16,384
    float*  fi   = ws + 58753024;                    // 16,384
    float*  d0   = ws + 58769408;                    // 16,384
    double* csd  = (double*)(ws + 58785792);         // 16,384 doubles
    double* wd   = (double*)(ws + 58818560);         // 16,384 doubles
    double* vd   = (double*)(ws + 58851328);         // 16,384 doubles
    double* dgvd = (double*)(ws + 58884096);         // 16,384 doubles
    double* a0c  = (double*)(ws + 58916864);         // 16,384 doubles
    double* frc  = (double*)(ws + 58949632);         // 16,384 doubles
    double* sd   = (double*)(ws + 58982400);         // 16 doubles; end ~236 MB

    float* r_out   = (float*)d_out;
    float* aki_out = r_out + (long)BB * KD * SS;

    k_prep<<<BB * KD * SS / 256, 256, 0, stream>>>(x, di, ei);
    k_gemm16<true, true><<<dim3(128, 3), 256, 0, stream>>>(di, Wp_w, Wp_b, uj, BB * KD, SS, SS);
    k_gemm16<true, true><<<dim3(128, 3), 256, 0, stream>>>(di, Wc_w, Wc_b, uk, BB * KD, SS, SS);
    k_firaw<<<BB * KD / 4, 256, 0, stream>>>(di, fi_w, g);
    k_gemm16<false, false><<<dim3(128, 3), 256, 0, stream>>>(uj, Wa_w, nullptr, tt, BB * KD, SS, SS);
    k_fjk16<<<dim3(8, 8, BB), 256, 0, stream>>>(tt, uk, A);
    k_colmax<<<BB * KD / 256, 256, 0, stream>>>(A, g, mcol);
    k_expA<<<BB * KD * KD / 256, 256, 0, stream>>>(A, mcol);
    k_fi2<<<BB * KD / 256, 256, 0, stream>>>(g, mcol, fi);
    k_colsum_d<<<BB * KD / 256, 256, 0, stream>>>(A, csd);
    k_buildT<<<BB * KD * KD / 256, 256, 0, stream>>>(A, csd, Td);

    for (int s = 0; s < KD / NBLK; s++) {
        int kb = s * NBLK;
        k_diag_d<<<BB, 256, 0, stream>>>(Td, kb);
        k_savecol_d<<<BB * KD * NBLK / 256, 256, 0, stream>>>(Td, Ftd, kb);
        k_rowcol_d<<<dim3(15, BB), 256, 0, stream>>>(Td, kb);
        k_elim_d<<<dim3(8, 16, BB), 256, 0, stream>>>(Td, Ftd, kb);
    }

    k_compact<<<BB * KD / 256, 256, 0, stream>>>(A, fi, a0c, frc);
    k_w<<<BB * KD / 4, 256, 0, stream>>>(Td, a0c, wd);
    k_v<<<dim3(4, BB), 256, 0, stream>>>(Td, frc, vd);
    k_s<<<BB, 64, 0, stream>>>(vd, a0c, fi, sd);
    k_dgv<<<BB * KD / 256, 256, 0, stream>>>(Td, wd, vd, sd, fi, dgvd, d0);
    k_aik2<<<dim3(16, 16, BB), 256, 0, stream>>>(A, Td, wd, vd, dgvd, sd);
    k_aki<<<dim3(16, 16, BB), 256, 0, stream>>>(A, d0, aki_out);
    k_si16<<<dim3(8, 3, BB), 256, 0, stream>>>(A, ei, d0, expar, sbuf);
    k_ci16<<<dim3(8, 3, BB), 256, 0, stream>>>(A, ei, cbuf);
    k_ri16<<<dim3(128, 3), 256, 0, stream>>>(ei, sbuf, cbuf, Wr_w, Wr_b, r_out);
}